// Round 2
// baseline (813.365 us; speedup 1.0000x reference)
//
#include <hip/hip_runtime.h>
#include <hip/hip_fp16.h>

// Problem constants
#define NB 2
#define NH 16
#define NS 2048
#define ND 64
// Tile: 64 rows per workgroup (16 per wave), 64-column K/V tiles
#define BM 64
#define BN 64
// LDS pitches in halves (+8 pad; rows stride 4 banks -> <=2-way)
#define KP 72
#define VP 72
#define PP 72

typedef _Float16 half8 __attribute__((ext_vector_type(8)));
typedef float f32x4 __attribute__((ext_vector_type(4)));

__global__ __launch_bounds__(256, 4)
void attn_fused(const float* __restrict__ qg, const float* __restrict__ kgl,
                const float* __restrict__ vgl, const float* __restrict__ dwm,
                const float* __restrict__ sig, float* __restrict__ out0,
                float* __restrict__ attn)
{
    __shared__ _Float16 Khi[BN * KP];   // K tile, fp16 high part
    __shared__ _Float16 Klo[BN * KP];   // K tile, fp16 residual (k - (float)khi)
    __shared__ _Float16 Vs[ND * VP];    // V transposed [d][t], XOR-swizzled 16B blocks
    __shared__ _Float16 Ps[BM * PP];    // per-wave 16-row private bands

    const int tid  = threadIdx.x;
    const int wave = tid >> 6;
    const int lane = tid & 63;
    const int quad = lane >> 4;
    const int lc   = lane & 15;

    const int mtile = blockIdx.x;   // 0..31 row tiles
    const int bh    = blockIdx.y;   // 0..31 (b,h)
    const int b     = bh >> 4;

    const float sv = sig[0];
    const float inv_s2 = 1.0f / (sv * sv);

    const float* qp = qg  + (size_t)bh * NS * ND + (size_t)mtile * BM * ND;
    const float* kp = kgl + (size_t)bh * NS * ND;
    const float* vp = vgl + (size_t)bh * NS * ND;
    const float* dp = dwm + (size_t)b  * NS * NS + (size_t)mtile * BM * NS;
    float* op = out0 + (size_t)bh * NS * ND + (size_t)mtile * BM * ND;
    float* ap = attn + (size_t)bh * NS * NS + (size_t)mtile * BM * NS;

    // ---- Q A-fragments, loaded directly from global, hi/lo fp16 split ----
    // A[m = lane&15][k = quad*8+j]; THIS WAVE's rows: wave*16 + lc  (round-0 bug fix)
    half8 aqh0, aql0, aqh1, aql1;
    {
        const float* qr = qp + (size_t)(wave * 16 + lc) * ND + quad * 8;
        float4 f0 = *(const float4*)qr;
        float4 f1 = *(const float4*)(qr + 4);
        float4 f2 = *(const float4*)(qr + 32);
        float4 f3 = *(const float4*)(qr + 36);
        float v0[8] = {f0.x, f0.y, f0.z, f0.w, f1.x, f1.y, f1.z, f1.w};
        float v1[8] = {f2.x, f2.y, f2.z, f2.w, f3.x, f3.y, f3.z, f3.w};
        #pragma unroll
        for (int j = 0; j < 8; j++) {
            float x = v0[j] * 0.125f;           // 1/TEMPERATURE, exact in fp32
            _Float16 h = (_Float16)x;
            aqh0[j] = h; aql0[j] = (_Float16)(x - (float)h);
            x = v1[j] * 0.125f;
            h = (_Float16)x;
            aqh1[j] = h; aql1[j] = (_Float16)(x - (float)h);
        }
    }

    auto stageK = [&](int t0) {
        const int r  = tid >> 2;          // 0..63 : t row
        const int ds = (tid & 3) * 16;    // 0,16,32,48 : d segment
        const float* s = kp + (size_t)(t0 + r) * ND + ds;
        float4 f0 = *(const float4*)s;
        float4 f1 = *(const float4*)(s + 4);
        float4 f2 = *(const float4*)(s + 8);
        float4 f3 = *(const float4*)(s + 12);
        float fv[16] = {f0.x, f0.y, f0.z, f0.w, f1.x, f1.y, f1.z, f1.w,
                        f2.x, f2.y, f2.z, f2.w, f3.x, f3.y, f3.z, f3.w};
        half8 h0, h1, l0, l1;
        #pragma unroll
        for (int i = 0; i < 8; i++) {
            _Float16 h = (_Float16)fv[i];
            h0[i] = h; l0[i] = (_Float16)(fv[i] - (float)h);
            h = (_Float16)fv[8 + i];
            h1[i] = h; l1[i] = (_Float16)(fv[8 + i] - (float)h);
        }
        *(half8*)&Khi[r * KP + ds]     = h0;
        *(half8*)&Khi[r * KP + ds + 8] = h1;
        *(half8*)&Klo[r * KP + ds]     = l0;
        *(half8*)&Klo[r * KP + ds + 8] = l1;
    };

    // V transposed (Vs[d][t]), two t per dword, 16B-block XOR swizzle on the
    // dword index: keeps ds_read_b128 alignment, caps conflicts at 2-way.
    auto stageV = [&](int t0) {
        const int tp = tid >> 3;         // 0..31 : t-pair
        const int ds = (tid & 7) * 8;    // 0..56 : d segment
        const float4* sa = (const float4*)(vp + (size_t)(t0 + 2 * tp) * ND + ds);
        const float4* sb = (const float4*)(vp + (size_t)(t0 + 2 * tp + 1) * ND + ds);
        float4 a0 = sa[0], a1 = sa[1];
        float4 b0 = sb[0], b1 = sb[1];
        float av[8] = {a0.x, a0.y, a0.z, a0.w, a1.x, a1.y, a1.z, a1.w};
        float bv[8] = {b0.x, b0.y, b0.z, b0.w, b1.x, b1.y, b1.z, b1.w};
        unsigned int* Vdw = (unsigned int*)Vs;
        #pragma unroll
        for (int i = 0; i < 8; i++) {
            const int d  = ds + i;
            const int dw = d * (VP / 2) + (tp ^ (((d >> 3) & 7) << 2));
            union { _Float16 h[2]; unsigned int u; } pk;
            pk.h[0] = (_Float16)av[i];
            pk.h[1] = (_Float16)bv[i];
            Vdw[dw] = pk.u;
        }
    };

    // ================= PASS A: row sums l = sum_t exp(|s*g|) =================
    float lsum[4] = {0.f, 0.f, 0.f, 0.f};

    for (int t0 = 0; t0 < NS; t0 += BN) {
        __syncthreads();
        stageK(t0);
        __syncthreads();
        #pragma unroll
        for (int n = 0; n < 4; n++) {
            const half8 kh0 = *(const half8*)&Khi[(n * 16 + lc) * KP + quad * 8];
            const half8 kh1 = *(const half8*)&Khi[(n * 16 + lc) * KP + quad * 8 + 32];
            const half8 kl0 = *(const half8*)&Klo[(n * 16 + lc) * KP + quad * 8];
            const half8 kl1 = *(const half8*)&Klo[(n * 16 + lc) * KP + quad * 8 + 32];
            f32x4 c = {0.f, 0.f, 0.f, 0.f};
            c = __builtin_amdgcn_mfma_f32_16x16x32_f16(aqh0, kh0, c, 0, 0, 0);
            c = __builtin_amdgcn_mfma_f32_16x16x32_f16(aqh1, kh1, c, 0, 0, 0);
            c = __builtin_amdgcn_mfma_f32_16x16x32_f16(aql0, kh0, c, 0, 0, 0);
            c = __builtin_amdgcn_mfma_f32_16x16x32_f16(aql1, kh1, c, 0, 0, 0);
            c = __builtin_amdgcn_mfma_f32_16x16x32_f16(aqh0, kl0, c, 0, 0, 0);
            c = __builtin_amdgcn_mfma_f32_16x16x32_f16(aqh1, kl1, c, 0, 0, 0);
            #pragma unroll
            for (int r2 = 0; r2 < 4; r2++) {
                const int lrow = wave * 16 + quad * 4 + r2;
                const int col  = t0 + n * 16 + lc;
                const float g = __expf(dp[(size_t)lrow * NS + col] * inv_s2);
                const float z = fabsf(c[r2] * g);
                lsum[r2] += __expf(z);   // z <= ~16: no max-subtract needed in fp32
            }
        }
    }

    #pragma unroll
    for (int r2 = 0; r2 < 4; r2++) {
        float s = lsum[r2];
        s += __shfl_xor(s, 1, 64);
        s += __shfl_xor(s, 2, 64);
        s += __shfl_xor(s, 4, 64);
        s += __shfl_xor(s, 8, 64);
        lsum[r2] = 1.0f / s;   // 1/l
    }

    // ============ PASS B: recompute scores, write attn, O += P*V ============
    f32x4 o[4];
    #pragma unroll
    for (int i = 0; i < 4; i++) o[i] = (f32x4){0.f, 0.f, 0.f, 0.f};

    for (int t0 = 0; t0 < NS; t0 += BN) {
        __syncthreads();
        stageK(t0);
        stageV(t0);
        __syncthreads();
        #pragma unroll
        for (int n = 0; n < 4; n++) {
            const half8 kh0 = *(const half8*)&Khi[(n * 16 + lc) * KP + quad * 8];
            const half8 kh1 = *(const half8*)&Khi[(n * 16 + lc) * KP + quad * 8 + 32];
            const half8 kl0 = *(const half8*)&Klo[(n * 16 + lc) * KP + quad * 8];
            const half8 kl1 = *(const half8*)&Klo[(n * 16 + lc) * KP + quad * 8 + 32];
            f32x4 c = {0.f, 0.f, 0.f, 0.f};
            c = __builtin_amdgcn_mfma_f32_16x16x32_f16(aqh0, kh0, c, 0, 0, 0);
            c = __builtin_amdgcn_mfma_f32_16x16x32_f16(aqh1, kh1, c, 0, 0, 0);
            c = __builtin_amdgcn_mfma_f32_16x16x32_f16(aql0, kh0, c, 0, 0, 0);
            c = __builtin_amdgcn_mfma_f32_16x16x32_f16(aql1, kh1, c, 0, 0, 0);
            c = __builtin_amdgcn_mfma_f32_16x16x32_f16(aqh0, kl0, c, 0, 0, 0);
            c = __builtin_amdgcn_mfma_f32_16x16x32_f16(aqh1, kl1, c, 0, 0, 0);
            #pragma unroll
            for (int r2 = 0; r2 < 4; r2++) {
                const int lrow = wave * 16 + quad * 4 + r2;
                const int col  = t0 + n * 16 + lc;
                const float g = __expf(dp[(size_t)lrow * NS + col] * inv_s2);
                const float z = fabsf(c[r2] * g);
                const float p = __expf(z) * lsum[r2];   // in [0,1]: fp16-safe
                Ps[(size_t)lrow * PP + n * 16 + lc] = (_Float16)p;
            }
        }
        // P: C-layout -> A-layout via wave-private LDS band (no barrier needed)
        const half8 pa0 = *(const half8*)&Ps[(wave * 16 + lc) * PP + quad * 8];
        const half8 pa1 = *(const half8*)&Ps[(wave * 16 + lc) * PP + quad * 8 + 32];

        // attn store from A-layout frags: 8-consecutive-column f32x4 runs
        {
            float* arow = ap + (size_t)(wave * 16 + lc) * NS + t0 + quad * 8;
            f32x4 s0 = {(float)pa0[0], (float)pa0[1], (float)pa0[2], (float)pa0[3]};
            f32x4 s1 = {(float)pa0[4], (float)pa0[5], (float)pa0[6], (float)pa0[7]};
            f32x4 s2 = {(float)pa1[0], (float)pa1[1], (float)pa1[2], (float)pa1[3]};
            f32x4 s3 = {(float)pa1[4], (float)pa1[5], (float)pa1[6], (float)pa1[7]};
            __builtin_nontemporal_store(s0, (f32x4*)arow);
            __builtin_nontemporal_store(s1, (f32x4*)(arow + 4));
            __builtin_nontemporal_store(s2, (f32x4*)(arow + 32));
            __builtin_nontemporal_store(s3, (f32x4*)(arow + 36));
        }

        #pragma unroll
        for (int n2 = 0; n2 < 4; n2++) {
            const int dv  = n2 * 16 + lc;
            const int fd  = ((dv >> 3) & 7) << 2;
            const int dwb = dv * (VP / 2);
            const half8 bv0 = *(const half8*)((const char*)Vs +
                               (size_t)((dwb + ((quad * 4) ^ fd)) * 4));
            const half8 bv1 = *(const half8*)((const char*)Vs +
                               (size_t)((dwb + ((16 + quad * 4) ^ fd)) * 4));
            o[n2] = __builtin_amdgcn_mfma_f32_16x16x32_f16(pa0, bv0, o[n2], 0, 0, 0);
            o[n2] = __builtin_amdgcn_mfma_f32_16x16x32_f16(pa1, bv1, o[n2], 0, 0, 0);
        }
    }

    // ---- epilogue: write O ----
    #pragma unroll
    for (int n2 = 0; n2 < 4; n2++) {
        #pragma unroll
        for (int r2 = 0; r2 < 4; r2++) {
            const int lrow = wave * 16 + quad * 4 + r2;
            __builtin_nontemporal_store(o[n2][r2],
                                        &op[(size_t)lrow * ND + n2 * 16 + lc]);
        }
    }
}

extern "C" void kernel_launch(void* const* d_in, const int* in_sizes, int n_in,
                              void* d_out, int out_size, void* d_ws, size_t ws_size,
                              hipStream_t stream) {
    (void)in_sizes; (void)n_in; (void)out_size; (void)d_ws; (void)ws_size;
    const float* q   = (const float*)d_in[0];
    const float* k   = (const float*)d_in[1];
    const float* v   = (const float*)d_in[2];
    const float* dwm = (const float*)d_in[3];
    const float* sig = (const float*)d_in[4];
    float* out0 = (float*)d_out;
    float* attn = out0 + (size_t)NB * NH * NS * ND;   // outputs concatenated flat
    dim3 grid(NS / BM, NB * NH);
    attn_fused<<<grid, dim3(256), 0, stream>>>(q, k, v, dwm, sig, out0, attn);
}